// Round 1
// baseline (566.082 us; speedup 1.0000x reference)
//
#include <hip/hip_runtime.h>

#define NN 50000
#define HID 128
#define NEG_SLOPE 0.2f

// ---------------- graph build ----------------

__global__ void init_deg_kernel(int* deg, int n) {
  int i = blockIdx.x * blockDim.x + threadIdx.x;
  if (i < n) deg[i] = 1;  // self loop
}

__global__ void count_kernel(const int* __restrict__ dst, int* deg, int e) {
  int i = blockIdx.x * blockDim.x + threadIdx.x;
  if (i < e) atomicAdd(&deg[dst[i]], 1);
}

__global__ __launch_bounds__(1024) void scan_kernel(const int* __restrict__ deg,
                                                    int* row_ptr, int* cursor, int n) {
  __shared__ int sums[1024];
  int t = threadIdx.x;
  const int CH = (n + 1023) / 1024;
  int lo = t * CH;
  int hi = lo + CH; if (hi > n) hi = n;
  int s = 0;
  for (int i = lo; i < hi; ++i) s += deg[i];
  sums[t] = s;
  __syncthreads();
  // Hillis-Steele inclusive scan over 1024 thread sums
  for (int off = 1; off < 1024; off <<= 1) {
    int v = (t >= off) ? sums[t - off] : 0;
    __syncthreads();
    sums[t] += v;
    __syncthreads();
  }
  int excl = (t == 0) ? 0 : sums[t - 1];
  for (int i = lo; i < hi; ++i) {
    row_ptr[i] = excl;
    cursor[i] = excl;
    excl += deg[i];
  }
  if (t == 1023) row_ptr[n] = sums[1023];
}

__global__ void scatter_kernel(const int* __restrict__ src, const int* __restrict__ dst,
                               int* cursor, int* src_sorted, int e, int n) {
  int i = blockIdx.x * blockDim.x + threadIdx.x;
  if (i < e) {
    int d = dst[i];
    int pos = atomicAdd(&cursor[d], 1);
    src_sorted[pos] = src[i];
  } else if (i < e + n) {
    int v = i - e;
    int pos = atomicAdd(&cursor[v], 1);
    src_sorted[pos] = v;
  }
}

// ---------------- dense pieces ----------------

// v[i] = sum_j w_dst[i*hid + j] * att_dst[j], i < din
__global__ void vdst_kernel(const float* __restrict__ w_dst,
                            const float* __restrict__ att_dst,
                            float* v, int din, int hid) {
  int i = blockIdx.x * blockDim.x + threadIdx.x;
  if (i < din) {
    float s = 0.f;
    for (int j = 0; j < hid; ++j) s += w_dst[i * hid + j] * att_dst[j];
    v[i] = s;
  }
}

// C[M,128] = A[M,K] @ B[K,128].  128x128 tile, BK=8, 256 threads, 8x8 microtile.
__global__ __launch_bounds__(256) void sgemm128(const float* __restrict__ A,
                                                const float* __restrict__ B,
                                                float* __restrict__ C,
                                                int M, int K) {
  __shared__ float As[8][128];   // [k][row] transposed
  __shared__ float Bs[8][128];   // [k][col]
  int tid = threadIdx.x;
  int row0 = blockIdx.x * 128;
  int tx = tid & 15, ty = tid >> 4;

  float acc[8][8];
#pragma unroll
  for (int i = 0; i < 8; ++i)
#pragma unroll
    for (int j = 0; j < 8; ++j) acc[i][j] = 0.f;

  for (int k0 = 0; k0 < K; k0 += 8) {
    {
      int r = tid >> 1, q = (tid & 1) * 4;
      int row = row0 + r;
      float4 v = make_float4(0.f, 0.f, 0.f, 0.f);
      if (row < M) v = *reinterpret_cast<const float4*>(&A[(size_t)row * K + k0 + q]);
      As[q + 0][r] = v.x; As[q + 1][r] = v.y; As[q + 2][r] = v.z; As[q + 3][r] = v.w;
    }
    {
      int r = tid >> 5, c = (tid & 31) * 4;
      *reinterpret_cast<float4*>(&Bs[r][c]) =
          *reinterpret_cast<const float4*>(&B[(size_t)(k0 + r) * 128 + c]);
    }
    __syncthreads();
#pragma unroll
    for (int k = 0; k < 8; ++k) {
      float4 a0 = *reinterpret_cast<const float4*>(&As[k][ty * 8]);
      float4 a1 = *reinterpret_cast<const float4*>(&As[k][ty * 8 + 4]);
      float4 b0 = *reinterpret_cast<const float4*>(&Bs[k][tx * 8]);
      float4 b1 = *reinterpret_cast<const float4*>(&Bs[k][tx * 8 + 4]);
      float a[8] = {a0.x, a0.y, a0.z, a0.w, a1.x, a1.y, a1.z, a1.w};
      float b[8] = {b0.x, b0.y, b0.z, b0.w, b1.x, b1.y, b1.z, b1.w};
#pragma unroll
      for (int i = 0; i < 8; ++i)
#pragma unroll
        for (int j = 0; j < 8; ++j) acc[i][j] += a[i] * b[j];
    }
    __syncthreads();
  }
#pragma unroll
  for (int i = 0; i < 8; ++i) {
    int row = row0 + ty * 8 + i;
    if (row < M) {
      float4 o0 = make_float4(acc[i][0], acc[i][1], acc[i][2], acc[i][3]);
      float4 o1 = make_float4(acc[i][4], acc[i][5], acc[i][6], acc[i][7]);
      *reinterpret_cast<float4*>(&C[(size_t)row * 128 + tx * 8]) = o0;
      *reinterpret_cast<float4*>(&C[(size_t)row * 128 + tx * 8 + 4]) = o1;
    }
  }
}

// per-node logits: a_s[n] = xs[n]·att_src (128), a_d[n] = xin[n]·v_dst (din)
__global__ __launch_bounds__(256) void logits_kernel(const float* __restrict__ xs,
                                                     const float* __restrict__ xin,
                                                     const float* __restrict__ att_src,
                                                     const float* __restrict__ v_dst,
                                                     float* a_s, float* a_d,
                                                     int n, int din) {
  int wid = (blockIdx.x * blockDim.x + threadIdx.x) >> 6;
  int lane = threadIdx.x & 63;
  if (wid >= n) return;
  float s1 = xs[(size_t)wid * 128 + lane] * att_src[lane] +
             xs[(size_t)wid * 128 + 64 + lane] * att_src[64 + lane];
  float s2 = 0.f;
  for (int i = lane; i < din; i += 64) s2 += xin[(size_t)wid * din + i] * v_dst[i];
#pragma unroll
  for (int off = 32; off; off >>= 1) {
    s1 += __shfl_xor(s1, off);
    s2 += __shfl_xor(s2, off);
  }
  if (lane == 0) { a_s[wid] = s1; a_d[wid] = s2; }
}

// wave-per-node segment softmax + aggregate
__global__ __launch_bounds__(256) void agg_kernel(const int* __restrict__ row_ptr,
                                                  const int* __restrict__ src_sorted,
                                                  const float* __restrict__ a_s,
                                                  const float* __restrict__ a_d,
                                                  const float* __restrict__ xs,
                                                  const float* __restrict__ bias,
                                                  float* __restrict__ out,
                                                  int n, int do_relu) {
  int wid = (blockIdx.x * blockDim.x + threadIdx.x) >> 6;
  int lane = threadIdx.x & 63;
  if (wid >= n) return;
  int r0 = row_ptr[wid], r1 = row_ptr[wid + 1];
  float ad = a_d[wid];

  // pass 1: segment max
  float m = -1e30f;
  for (int i = r0 + lane; i < r1; i += 64) {
    int s = src_sorted[i];
    float e = a_s[s] + ad;
    e = e > 0.f ? e : NEG_SLOPE * e;
    m = fmaxf(m, e);
  }
#pragma unroll
  for (int off = 32; off; off >>= 1) m = fmaxf(m, __shfl_xor(m, off));

  // pass 2: weighted accumulate
  float denom = 0.f, acc0 = 0.f, acc1 = 0.f;
  for (int i = r0; i < r1; ++i) {
    int s = src_sorted[i];
    float e = a_s[s] + ad;
    e = e > 0.f ? e : NEG_SLOPE * e;
    float w = __expf(e - m);
    denom += w;
    acc0 += w * xs[(size_t)s * 128 + lane];
    acc1 += w * xs[(size_t)s * 128 + 64 + lane];
  }
  float inv = 1.0f / denom;
  float o0 = acc0 * inv + bias[lane];
  float o1 = acc1 * inv + bias[64 + lane];
  if (do_relu) { o0 = fmaxf(o0, 0.f); o1 = fmaxf(o1, 0.f); }
  out[(size_t)wid * 128 + lane] = o0;
  out[(size_t)wid * 128 + 64 + lane] = o1;
}

// ---------------- launch ----------------

extern "C" void kernel_launch(void* const* d_in, const int* in_sizes, int n_in,
                              void* d_out, int out_size, void* d_ws, size_t ws_size,
                              hipStream_t stream) {
  const float* x        = (const float*)d_in[0];
  const int*   eidx     = (const int*)d_in[1];
  const float* w1_src   = (const float*)d_in[2];
  const float* w1_dst   = (const float*)d_in[3];
  const float* att1_src = (const float*)d_in[4];
  const float* att1_dst = (const float*)d_in[5];
  const float* b1       = (const float*)d_in[6];
  const float* w2_src   = (const float*)d_in[7];
  const float* w2_dst   = (const float*)d_in[8];
  const float* att2_src = (const float*)d_in[9];
  const float* att2_dst = (const float*)d_in[10];
  const float* b2       = (const float*)d_in[11];
  float* out = (float*)d_out;

  const int E = in_sizes[1] / 2;
  const int DIN = in_sizes[0] / NN;   // 256
  const int* src = eidx;
  const int* dst = eidx + E;

  char* ws = (char*)d_ws;
  size_t off = 0;
  auto alloc = [&](size_t bytes) -> void* {
    void* p = ws + off;
    off = (off + bytes + 255) & ~(size_t)255;
    return p;
  };
  float* xs         = (float*)alloc((size_t)NN * 128 * sizeof(float));
  float* a_s        = (float*)alloc((size_t)NN * sizeof(float));
  float* a_d        = (float*)alloc((size_t)NN * sizeof(float));
  int*   deg        = (int*)alloc((size_t)NN * sizeof(int));
  int*   cursor     = (int*)alloc((size_t)NN * sizeof(int));
  int*   row_ptr    = (int*)alloc((size_t)(NN + 1) * sizeof(int));
  int*   src_sorted = (int*)alloc((size_t)(E + NN) * sizeof(int));
  float* vd         = (float*)alloc(256 * sizeof(float));

  // graph build (shared by both layers)
  init_deg_kernel<<<(NN + 255) / 256, 256, 0, stream>>>(deg, NN);
  count_kernel<<<(E + 255) / 256, 256, 0, stream>>>(dst, deg, E);
  scan_kernel<<<1, 1024, 0, stream>>>(deg, row_ptr, cursor, NN);
  scatter_kernel<<<(E + NN + 255) / 256, 256, 0, stream>>>(src, dst, cursor, src_sorted, E, NN);

  const int wave_blocks = (NN * 64 + 255) / 256;   // one wave per node
  const int gemm_blocks = (NN + 127) / 128;

  // ---- layer 1 ----
  vdst_kernel<<<1, 256, 0, stream>>>(w1_dst, att1_dst, vd, DIN, HID);
  sgemm128<<<gemm_blocks, 256, 0, stream>>>(x, w1_src, xs, NN, DIN);
  logits_kernel<<<wave_blocks, 256, 0, stream>>>(xs, x, att1_src, vd, a_s, a_d, NN, DIN);
  agg_kernel<<<wave_blocks, 256, 0, stream>>>(row_ptr, src_sorted, a_s, a_d, xs, b1, out, NN, 1);

  // ---- layer 2 ----  (h lives in d_out; agg2 overwrites d_out, never reads it)
  vdst_kernel<<<1, 256, 0, stream>>>(w2_dst, att2_dst, vd, HID, HID);
  sgemm128<<<gemm_blocks, 256, 0, stream>>>(out, w2_src, xs, NN, HID);
  logits_kernel<<<wave_blocks, 256, 0, stream>>>(xs, out, att2_src, vd, a_s, a_d, NN, HID);
  agg_kernel<<<wave_blocks, 256, 0, stream>>>(row_ptr, src_sorted, a_s, a_d, xs, b2, out, NN, 0);
}

// Round 2
// 390.564 us; speedup vs baseline: 1.4494x; 1.4494x over previous
//
#include <hip/hip_runtime.h>

#define NN 50000
#define NEG_SLOPE 0.2f

typedef _Float16 half8 __attribute__((ext_vector_type(8)));
typedef _Float16 half2v __attribute__((ext_vector_type(2)));
typedef float floatx4 __attribute__((ext_vector_type(4)));

// ---------------- f32 -> f16 convert (8 elem/thread) ----------------
__global__ void cvt_kernel(const float* __restrict__ in, _Float16* __restrict__ out, int n8) {
  int i = blockIdx.x * blockDim.x + threadIdx.x;
  if (i >= n8) return;
  const float4* p = reinterpret_cast<const float4*>(in) + i * 2;
  float4 v0 = p[0], v1 = p[1];
  half8 h = {(_Float16)v0.x, (_Float16)v0.y, (_Float16)v0.z, (_Float16)v0.w,
             (_Float16)v1.x, (_Float16)v1.y, (_Float16)v1.z, (_Float16)v1.w};
  *reinterpret_cast<half8*>(out + (size_t)i * 8) = h;
}

// ---------------- graph build ----------------
__global__ void init_deg_kernel(int* deg, int n) {
  int i = blockIdx.x * blockDim.x + threadIdx.x;
  if (i < n) deg[i] = 1;  // self loop
}

__global__ void count_kernel(const int* __restrict__ dst, int* deg, int e) {
  int i = blockIdx.x * blockDim.x + threadIdx.x;
  if (i < e) atomicAdd(&deg[dst[i]], 1);
}

__global__ __launch_bounds__(256) void block_sums_kernel(const int* __restrict__ deg,
                                                         int* bsum, int n) {
  __shared__ int sh[256];
  int t = threadIdx.x;
  int i = blockIdx.x * 256 + t;
  sh[t] = (i < n) ? deg[i] : 0;
  __syncthreads();
  for (int off = 128; off; off >>= 1) {
    if (t < off) sh[t] += sh[t + off];
    __syncthreads();
  }
  if (t == 0) bsum[blockIdx.x] = sh[0];
}

// single small block: exclusive offsets of block sums + total -> row_ptr[n]
__global__ __launch_bounds__(256) void scan_bsums_kernel(const int* __restrict__ bsum,
                                                         int* boff, int* row_ptr,
                                                         int nb, int n) {
  __shared__ int sh[256];
  int t = threadIdx.x;
  int orig = (t < nb) ? bsum[t] : 0;
  sh[t] = orig;
  __syncthreads();
  for (int off = 1; off < 256; off <<= 1) {
    int v = (t >= off) ? sh[t - off] : 0;
    __syncthreads();
    sh[t] += v;
    __syncthreads();
  }
  if (t < nb) boff[t] = sh[t] - orig;
  if (t == nb - 1) row_ptr[n] = sh[t];
}

__global__ __launch_bounds__(256) void emit_kernel(const int* __restrict__ deg,
                                                   const int* __restrict__ boff,
                                                   int* row_ptr, int* cursor, int n) {
  __shared__ int sh[256];
  int t = threadIdx.x;
  int i = blockIdx.x * 256 + t;
  int d = (i < n) ? deg[i] : 0;
  sh[t] = d;
  __syncthreads();
  for (int off = 1; off < 256; off <<= 1) {
    int v = (t >= off) ? sh[t - off] : 0;
    __syncthreads();
    sh[t] += v;
    __syncthreads();
  }
  int excl = sh[t] - d + boff[blockIdx.x];
  if (i < n) { row_ptr[i] = excl; cursor[i] = excl; }
}

__global__ void scatter_kernel(const int* __restrict__ src, const int* __restrict__ dst,
                               int* cursor, int* src_sorted, int e, int n) {
  int i = blockIdx.x * blockDim.x + threadIdx.x;
  if (i < e) {
    int d = dst[i];
    int pos = atomicAdd(&cursor[d], 1);
    src_sorted[pos] = src[i];
  } else if (i < e + n) {
    int v = i - e;
    int pos = atomicAdd(&cursor[v], 1);
    src_sorted[pos] = v;
  }
}

// ---------------- dense pieces ----------------
// v[i] = sum_j w_dst[i*hid + j] * att_dst[j]
__global__ void vdst_kernel(const float* __restrict__ w_dst,
                            const float* __restrict__ att_dst,
                            float* v, int din, int hid) {
  int i = blockIdx.x * blockDim.x + threadIdx.x;
  if (i < din) {
    float s = 0.f;
    for (int j = 0; j < hid; ++j) s += w_dst[i * hid + j] * att_dst[j];
    v[i] = s;
  }
}

// C[M,128](f16) = A[M,K](f16) @ B[K,128](f32->f16). 128x128 tile, 4 waves x (32x128).
// mfma_f32_16x16x32_f16: A frag lane l: row=l&15, k=8*(l>>4)+i ; B frag: col=l&15, same k.
// C/D: col=lane&15, row=(lane>>4)*4+reg.
template <int K>
__global__ __launch_bounds__(256) void gemm_mfma(const _Float16* __restrict__ A,
                                                 const float* __restrict__ B,
                                                 _Float16* __restrict__ C, int M) {
  constexpr int KP = K + 8;  // pad: 2-way max bank aliasing (free)
  __shared__ _Float16 Bt[128 * KP];  // B^T [col][k]
  int tid = threadIdx.x;
  for (int idx = tid; idx < K * 128; idx += 256) {
    int k = idx >> 7, c = idx & 127;
    Bt[c * KP + k] = (_Float16)B[idx];
  }
  __syncthreads();

  int lane = tid & 63, wave = tid >> 6;
  int row_base = blockIdx.x * 128 + wave * 32;
  int lr = lane & 15, lk = lane >> 4;  // 0..3

  floatx4 acc[2][8];
#pragma unroll
  for (int fm = 0; fm < 2; ++fm)
#pragma unroll
    for (int n = 0; n < 8; ++n) acc[fm][n] = {0.f, 0.f, 0.f, 0.f};

  for (int k0 = 0; k0 < K; k0 += 32) {
    half8 a[2];
#pragma unroll
    for (int fm = 0; fm < 2; ++fm) {
      int row = row_base + fm * 16 + lr;
      half8 af = {0, 0, 0, 0, 0, 0, 0, 0};
      if (row < M) af = *reinterpret_cast<const half8*>(&A[(size_t)row * K + k0 + lk * 8]);
      a[fm] = af;
    }
    half8 b[8];
#pragma unroll
    for (int n = 0; n < 8; ++n)
      b[n] = *reinterpret_cast<const half8*>(&Bt[(n * 16 + lr) * KP + k0 + lk * 8]);
#pragma unroll
    for (int fm = 0; fm < 2; ++fm)
#pragma unroll
      for (int n = 0; n < 8; ++n)
        acc[fm][n] = __builtin_amdgcn_mfma_f32_16x16x32_f16(a[fm], b[n], acc[fm][n], 0, 0, 0);
  }

#pragma unroll
  for (int fm = 0; fm < 2; ++fm)
#pragma unroll
    for (int n = 0; n < 8; ++n)
#pragma unroll
      for (int r = 0; r < 4; ++r) {
        int row = row_base + fm * 16 + lk * 4 + r;
        if (row < M) C[(size_t)row * 128 + n * 16 + lr] = (_Float16)acc[fm][n][r];
      }
}

// per-node logits: a_s[n] = xs[n](128,f16)·att_src, a_d[n] = xin[n](din,f16)·v_dst
__global__ __launch_bounds__(256) void logits_kernel(const _Float16* __restrict__ xs,
                                                     const _Float16* __restrict__ xin,
                                                     const float* __restrict__ att_src,
                                                     const float* __restrict__ v_dst,
                                                     float* a_s, float* a_d,
                                                     int n, int din) {
  int wid = (blockIdx.x * blockDim.x + threadIdx.x) >> 6;
  int lane = threadIdx.x & 63;
  if (wid >= n) return;
  half2v v1 = *reinterpret_cast<const half2v*>(&xs[(size_t)wid * 128 + 2 * lane]);
  float s1 = (float)v1[0] * att_src[2 * lane] + (float)v1[1] * att_src[2 * lane + 1];
  float s2 = 0.f;
  const half2v* xr = reinterpret_cast<const half2v*>(&xin[(size_t)wid * din]);
  for (int i = lane; i < din / 2; i += 64) {
    half2v v = xr[i];
    s2 += (float)v[0] * v_dst[2 * i] + (float)v[1] * v_dst[2 * i + 1];
  }
#pragma unroll
  for (int off = 32; off; off >>= 1) {
    s1 += __shfl_xor(s1, off);
    s2 += __shfl_xor(s2, off);
  }
  if (lane == 0) { a_s[wid] = s1; a_d[wid] = s2; }
}

// wave-per-node segment softmax + aggregate; lane owns 2 adjacent channels.
// LAYER==1: out f16 + relu.  LAYER==2: out f32, no relu.
template <int LAYER>
__global__ __launch_bounds__(256) void agg_kernel(const int* __restrict__ row_ptr,
                                                  const int* __restrict__ src_sorted,
                                                  const float* __restrict__ a_s,
                                                  const float* __restrict__ a_d,
                                                  const _Float16* __restrict__ xs,
                                                  const float* __restrict__ bias,
                                                  void* __restrict__ outp, int n) {
  int wid = (blockIdx.x * blockDim.x + threadIdx.x) >> 6;
  int lane = threadIdx.x & 63;
  if (wid >= n) return;
  int r0 = row_ptr[wid], r1 = row_ptr[wid + 1];
  float ad = a_d[wid];

  float m = -1e30f;
  for (int i = r0 + lane; i < r1; i += 64) {
    int s = src_sorted[i];
    float e = a_s[s] + ad;
    e = e > 0.f ? e : NEG_SLOPE * e;
    m = fmaxf(m, e);
  }
#pragma unroll
  for (int off = 32; off; off >>= 1) m = fmaxf(m, __shfl_xor(m, off));

  float denom = 0.f, acc0 = 0.f, acc1 = 0.f;
  for (int i = r0; i < r1; ++i) {
    int s = src_sorted[i];
    float e = a_s[s] + ad;
    e = e > 0.f ? e : NEG_SLOPE * e;
    float w = __expf(e - m);
    denom += w;
    half2v v = *reinterpret_cast<const half2v*>(&xs[(size_t)s * 128 + 2 * lane]);
    acc0 += w * (float)v[0];
    acc1 += w * (float)v[1];
  }
  float inv = 1.0f / denom;
  float o0 = acc0 * inv + bias[2 * lane];
  float o1 = acc1 * inv + bias[2 * lane + 1];
  if (LAYER == 1) {
    o0 = fmaxf(o0, 0.f);
    o1 = fmaxf(o1, 0.f);
    half2v h = {(_Float16)o0, (_Float16)o1};
    *reinterpret_cast<half2v*>(&((_Float16*)outp)[(size_t)wid * 128 + 2 * lane]) = h;
  } else {
    float2 f = make_float2(o0, o1);
    *reinterpret_cast<float2*>(&((float*)outp)[(size_t)wid * 128 + 2 * lane]) = f;
  }
}

// ---------------- launch ----------------
extern "C" void kernel_launch(void* const* d_in, const int* in_sizes, int n_in,
                              void* d_out, int out_size, void* d_ws, size_t ws_size,
                              hipStream_t stream) {
  const float* x        = (const float*)d_in[0];
  const int*   eidx     = (const int*)d_in[1];
  const float* w1_src   = (const float*)d_in[2];
  const float* w1_dst   = (const float*)d_in[3];
  const float* att1_src = (const float*)d_in[4];
  const float* att1_dst = (const float*)d_in[5];
  const float* b1       = (const float*)d_in[6];
  const float* w2_src   = (const float*)d_in[7];
  const float* w2_dst   = (const float*)d_in[8];
  const float* att2_src = (const float*)d_in[9];
  const float* att2_dst = (const float*)d_in[10];
  const float* b2       = (const float*)d_in[11];

  const int E = in_sizes[1] / 2;
  const int DIN = in_sizes[0] / NN;  // 256
  const int* src = eidx;
  const int* dst = eidx + E;

  // d_out doubles as f16 scratch: x_h [NN,256] f16 == 25.6MB == d_out size.
  // h (layer-1 out, f16 [NN,128]) overwrites x_h's dead first half; final agg
  // rewrites all of d_out in f32.
  _Float16* x_h = (_Float16*)d_out;
  _Float16* h_h = (_Float16*)d_out;
  float*    out = (float*)d_out;

  char* ws = (char*)d_ws;
  size_t off = 0;
  auto alloc = [&](size_t bytes) -> void* {
    void* p = ws + off;
    off = (off + bytes + 255) & ~(size_t)255;
    return p;
  };
  _Float16* xs_h     = (_Float16*)alloc((size_t)NN * 128 * sizeof(_Float16));
  float* a_s         = (float*)alloc((size_t)NN * sizeof(float));
  float* a_d         = (float*)alloc((size_t)NN * sizeof(float));
  int*   deg         = (int*)alloc((size_t)NN * sizeof(int));
  int*   cursor      = (int*)alloc((size_t)NN * sizeof(int));
  int*   row_ptr     = (int*)alloc((size_t)(NN + 1) * sizeof(int));
  int*   src_sorted  = (int*)alloc((size_t)(E + NN) * sizeof(int));
  int*   bsum        = (int*)alloc(256 * sizeof(int));
  int*   boff        = (int*)alloc(256 * sizeof(int));
  float* vd1         = (float*)alloc(256 * sizeof(float));
  float* vd2         = (float*)alloc(256 * sizeof(float));

  const int NB = (NN + 255) / 256;  // 196

  // x -> f16
  cvt_kernel<<<(NN * DIN / 8 + 255) / 256, 256, 0, stream>>>(x, x_h, NN * DIN / 8);

  // graph build
  init_deg_kernel<<<(NN + 255) / 256, 256, 0, stream>>>(deg, NN);
  count_kernel<<<(E + 255) / 256, 256, 0, stream>>>(dst, deg, E);
  block_sums_kernel<<<NB, 256, 0, stream>>>(deg, bsum, NN);
  scan_bsums_kernel<<<1, 256, 0, stream>>>(bsum, boff, row_ptr, NB, NN);
  emit_kernel<<<NB, 256, 0, stream>>>(deg, boff, row_ptr, cursor, NN);
  scatter_kernel<<<(E + NN + 255) / 256, 256, 0, stream>>>(src, dst, cursor, src_sorted, E, NN);

  const int wave_blocks = (NN * 64 + 255) / 256;
  const int gemm_blocks = (NN + 127) / 128;

  // ---- layer 1 ----
  vdst_kernel<<<1, 256, 0, stream>>>(w1_dst, att1_dst, vd1, DIN, 128);
  gemm_mfma<256><<<gemm_blocks, 256, 0, stream>>>(x_h, w1_src, xs_h, NN);
  logits_kernel<<<wave_blocks, 256, 0, stream>>>(xs_h, x_h, att1_src, vd1, a_s, a_d, NN, DIN);
  agg_kernel<1><<<wave_blocks, 256, 0, stream>>>(row_ptr, src_sorted, a_s, a_d, xs_h, b1, h_h, NN);

  // ---- layer 2 ----
  vdst_kernel<<<1, 256, 0, stream>>>(w2_dst, att2_dst, vd2, 128, 128);
  gemm_mfma<128><<<gemm_blocks, 256, 0, stream>>>(h_h, w2_src, xs_h, NN);
  logits_kernel<<<wave_blocks, 256, 0, stream>>>(xs_h, h_h, att2_src, vd2, a_s, a_d, NN, 128);
  agg_kernel<2><<<wave_blocks, 256, 0, stream>>>(row_ptr, src_sorted, a_s, a_d, xs_h, b2, out, NN);
}

// Round 3
// 240.160 us; speedup vs baseline: 2.3571x; 1.6263x over previous
//
#include <hip/hip_runtime.h>

#define NN 50000
#define NEG_SLOPE 0.2f

typedef _Float16 half8 __attribute__((ext_vector_type(8)));
typedef _Float16 half2v __attribute__((ext_vector_type(2)));
typedef float floatx4 __attribute__((ext_vector_type(4)));

// ---------------- f32 -> f16 convert (8 elem/thread) ----------------
__global__ void cvt_kernel(const float* __restrict__ in, _Float16* __restrict__ out, int n8) {
  int i = blockIdx.x * blockDim.x + threadIdx.x;
  if (i >= n8) return;
  const float4* p = reinterpret_cast<const float4*>(in) + i * 2;
  float4 v0 = p[0], v1 = p[1];
  half8 h = {(_Float16)v0.x, (_Float16)v0.y, (_Float16)v0.z, (_Float16)v0.w,
             (_Float16)v1.x, (_Float16)v1.y, (_Float16)v1.z, (_Float16)v1.w};
  *reinterpret_cast<half8*>(out + (size_t)i * 8) = h;
}

// ---------------- graph build ----------------
__global__ void init_deg_kernel(int* deg, int n) {
  int i = blockIdx.x * blockDim.x + threadIdx.x;
  if (i < n) deg[i] = 1;  // self loop
}

__global__ void count_kernel(const int* __restrict__ dst, int* deg, int e) {
  int i = blockIdx.x * blockDim.x + threadIdx.x;
  if (i < e) atomicAdd(&deg[dst[i]], 1);
}

__global__ __launch_bounds__(256) void block_sums_kernel(const int* __restrict__ deg,
                                                         int* bsum, int n) {
  __shared__ int sh[256];
  int t = threadIdx.x;
  int i = blockIdx.x * 256 + t;
  sh[t] = (i < n) ? deg[i] : 0;
  __syncthreads();
  for (int off = 128; off; off >>= 1) {
    if (t < off) sh[t] += sh[t + off];
    __syncthreads();
  }
  if (t == 0) bsum[blockIdx.x] = sh[0];
}

__global__ __launch_bounds__(256) void scan_bsums_kernel(const int* __restrict__ bsum,
                                                         int* boff, int* row_ptr,
                                                         int nb, int n) {
  __shared__ int sh[256];
  int t = threadIdx.x;
  int orig = (t < nb) ? bsum[t] : 0;
  sh[t] = orig;
  __syncthreads();
  for (int off = 1; off < 256; off <<= 1) {
    int v = (t >= off) ? sh[t - off] : 0;
    __syncthreads();
    sh[t] += v;
    __syncthreads();
  }
  if (t < nb) boff[t] = sh[t] - orig;
  if (t == nb - 1) row_ptr[n] = sh[t];
}

__global__ __launch_bounds__(256) void emit_kernel(const int* __restrict__ deg,
                                                   const int* __restrict__ boff,
                                                   int* row_ptr, int* cursor, int n) {
  __shared__ int sh[256];
  int t = threadIdx.x;
  int i = blockIdx.x * 256 + t;
  int d = (i < n) ? deg[i] : 0;
  sh[t] = d;
  __syncthreads();
  for (int off = 1; off < 256; off <<= 1) {
    int v = (t >= off) ? sh[t - off] : 0;
    __syncthreads();
    sh[t] += v;
    __syncthreads();
  }
  int excl = sh[t] - d + boff[blockIdx.x];
  if (i < n) { row_ptr[i] = excl; cursor[i] = excl; }
}

__global__ void scatter_kernel(const int* __restrict__ src, const int* __restrict__ dst,
                               int* cursor, int* src_sorted, int e, int n) {
  int i = blockIdx.x * blockDim.x + threadIdx.x;
  if (i < e) {
    int d = dst[i];
    int pos = atomicAdd(&cursor[d], 1);
    src_sorted[pos] = src[i];
  } else if (i < e + n) {
    int v = i - e;
    int pos = atomicAdd(&cursor[v], 1);
    src_sorted[pos] = v;
  }
}

// ---------------- projection vectors u = W_src@att_src, v = W_dst@att_dst ----------------
// block 0: u1 (din), 1: v1 (din), 2: u2 (128), 3: v2 (128). hid == 128 always.
__global__ __launch_bounds__(256) void uv_kernel(const float* __restrict__ w1s, const float* __restrict__ a1s,
                                                 const float* __restrict__ w1d, const float* __restrict__ a1d,
                                                 const float* __restrict__ w2s, const float* __restrict__ a2s,
                                                 const float* __restrict__ w2d, const float* __restrict__ a2d,
                                                 float* u1, float* v1, float* u2, float* v2, int din) {
  int b = blockIdx.x, i = threadIdx.x;
  const float *w, *a;
  float* o;
  int d;
  if (b == 0) { w = w1s; a = a1s; o = u1; d = din; }
  else if (b == 1) { w = w1d; a = a1d; o = v1; d = din; }
  else if (b == 2) { w = w2s; a = a2s; o = u2; d = 128; }
  else { w = w2d; a = a2d; o = v2; d = 128; }
  if (i < d) {
    float s = 0.f;
    for (int j = 0; j < 128; ++j) s += w[i * 128 + j] * a[j];
    o[i] = s;
  }
}

// ---------------- GEMM: C[M,128](f16) = A[M,K](f16) @ B[K,128](f32) ----------------
template <int K>
__global__ __launch_bounds__(256) void gemm_mfma(const _Float16* __restrict__ A,
                                                 const float* __restrict__ B,
                                                 _Float16* __restrict__ C, int M) {
  constexpr int KP = K + 8;
  __shared__ _Float16 Bt[128 * KP];  // B^T [col][k]
  int tid = threadIdx.x;
  for (int idx = tid; idx < K * 128; idx += 256) {
    int k = idx >> 7, c = idx & 127;
    Bt[c * KP + k] = (_Float16)B[idx];
  }
  __syncthreads();

  int lane = tid & 63, wave = tid >> 6;
  int row_base = blockIdx.x * 128 + wave * 32;
  int lr = lane & 15, lk = lane >> 4;

  floatx4 acc[2][8];
#pragma unroll
  for (int fm = 0; fm < 2; ++fm)
#pragma unroll
    for (int n = 0; n < 8; ++n) acc[fm][n] = {0.f, 0.f, 0.f, 0.f};

  for (int k0 = 0; k0 < K; k0 += 32) {
    half8 a[2];
#pragma unroll
    for (int fm = 0; fm < 2; ++fm) {
      int row = row_base + fm * 16 + lr;
      half8 af = {0, 0, 0, 0, 0, 0, 0, 0};
      if (row < M) af = *reinterpret_cast<const half8*>(&A[(size_t)row * K + k0 + lk * 8]);
      a[fm] = af;
    }
    half8 b[8];
#pragma unroll
    for (int n = 0; n < 8; ++n)
      b[n] = *reinterpret_cast<const half8*>(&Bt[(n * 16 + lr) * KP + k0 + lk * 8]);
#pragma unroll
    for (int fm = 0; fm < 2; ++fm)
#pragma unroll
      for (int n = 0; n < 8; ++n)
        acc[fm][n] = __builtin_amdgcn_mfma_f32_16x16x32_f16(a[fm], b[n], acc[fm][n], 0, 0, 0);
  }

#pragma unroll
  for (int fm = 0; fm < 2; ++fm)
#pragma unroll
    for (int n = 0; n < 8; ++n)
#pragma unroll
      for (int r = 0; r < 4; ++r) {
        int row = row_base + fm * 16 + lk * 4 + r;
        if (row < M) C[(size_t)row * 128 + n * 16 + lr] = (_Float16)acc[fm][n][r];
      }
}

// ---------------- per-node logits: a_s[n] = x[n]·u, a_d[n] = x[n]·v ----------------
__global__ __launch_bounds__(256) void logits_kernel(const _Float16* __restrict__ xin,
                                                     const float* __restrict__ u,
                                                     const float* __restrict__ v,
                                                     float* a_s, float* a_d,
                                                     int n, int din) {
  int wid = (blockIdx.x * blockDim.x + threadIdx.x) >> 6;
  int lane = threadIdx.x & 63;
  if (wid >= n) return;
  float s1 = 0.f, s2 = 0.f;
  const half2v* xr = reinterpret_cast<const half2v*>(&xin[(size_t)wid * din]);
  for (int i = lane; i < din / 2; i += 64) {
    half2v xv = xr[i];
    float x0 = (float)xv[0], x1 = (float)xv[1];
    s1 += x0 * u[2 * i] + x1 * u[2 * i + 1];
    s2 += x0 * v[2 * i] + x1 * v[2 * i + 1];
  }
#pragma unroll
  for (int off = 32; off; off >>= 1) {
    s1 += __shfl_xor(s1, off);
    s2 += __shfl_xor(s2, off);
  }
  if (lane == 0) { a_s[wid] = s1; a_d[wid] = s2; }
}

// ---------------- wave-per-node softmax-aggregate (no max pass) ----------------
// 4 groups of 16 lanes process every 4th edge; lane covers 8 channels (half8).
// LAYER==1: out f16 + relu.  LAYER==2: out f32.
template <int LAYER>
__global__ __launch_bounds__(256) void agg_kernel(const int* __restrict__ row_ptr,
                                                  const int* __restrict__ src_sorted,
                                                  const float* __restrict__ a_s,
                                                  const float* __restrict__ a_d,
                                                  const _Float16* __restrict__ xs,
                                                  const float* __restrict__ bias,
                                                  void* __restrict__ outp, int n) {
  int wid = (blockIdx.x * blockDim.x + threadIdx.x) >> 6;
  int lane = threadIdx.x & 63;
  if (wid >= n) return;
  int g = lane >> 4, lr = lane & 15;
  int r0 = row_ptr[wid], r1 = row_ptr[wid + 1];
  float ad = a_d[wid];

  float denom = 0.f;
  float acc[8];
#pragma unroll
  for (int j = 0; j < 8; ++j) acc[j] = 0.f;

  int i = r0 + g;
  int s_next = (i < r1) ? src_sorted[i] : -1;
  while (s_next >= 0) {
    int s = s_next;
    i += 4;
    s_next = (i < r1) ? src_sorted[i] : -1;  // prefetch next index
    float e = a_s[s] + ad;
    e = e > 0.f ? e : NEG_SLOPE * e;
    float w = __expf(e);
    denom += w;
    half8 vv = *reinterpret_cast<const half8*>(&xs[(size_t)s * 128 + lr * 8]);
#pragma unroll
    for (int j = 0; j < 8; ++j) acc[j] += w * (float)vv[j];
  }
  denom += __shfl_xor(denom, 16);
  denom += __shfl_xor(denom, 32);
#pragma unroll
  for (int j = 0; j < 8; ++j) {
    acc[j] += __shfl_xor(acc[j], 16);
    acc[j] += __shfl_xor(acc[j], 32);
  }
  if (g == 0) {
    float inv = 1.0f / denom;
    float o[8];
#pragma unroll
    for (int j = 0; j < 8; ++j) o[j] = acc[j] * inv + bias[lr * 8 + j];
    if (LAYER == 1) {
      half8 h;
#pragma unroll
      for (int j = 0; j < 8; ++j) h[j] = (_Float16)fmaxf(o[j], 0.f);
      *reinterpret_cast<half8*>(&((_Float16*)outp)[(size_t)wid * 128 + lr * 8]) = h;
    } else {
      float4 f0 = make_float4(o[0], o[1], o[2], o[3]);
      float4 f1 = make_float4(o[4], o[5], o[6], o[7]);
      float* op = &((float*)outp)[(size_t)wid * 128 + lr * 8];
      *reinterpret_cast<float4*>(op) = f0;
      *reinterpret_cast<float4*>(op + 4) = f1;
    }
  }
}

// ---------------- launch ----------------
extern "C" void kernel_launch(void* const* d_in, const int* in_sizes, int n_in,
                              void* d_out, int out_size, void* d_ws, size_t ws_size,
                              hipStream_t stream) {
  const float* x        = (const float*)d_in[0];
  const int*   eidx     = (const int*)d_in[1];
  const float* w1_src   = (const float*)d_in[2];
  const float* w1_dst   = (const float*)d_in[3];
  const float* att1_src = (const float*)d_in[4];
  const float* att1_dst = (const float*)d_in[5];
  const float* b1       = (const float*)d_in[6];
  const float* w2_src   = (const float*)d_in[7];
  const float* w2_dst   = (const float*)d_in[8];
  const float* att2_src = (const float*)d_in[9];
  const float* att2_dst = (const float*)d_in[10];
  const float* b2       = (const float*)d_in[11];

  const int E = in_sizes[1] / 2;
  const int DIN = in_sizes[0] / NN;  // 256
  const int* src = eidx;
  const int* dst = eidx + E;

  // d_out doubles as f16 scratch: x_h [NN,256] f16 == 25.6MB == d_out size.
  _Float16* x_h = (_Float16*)d_out;
  _Float16* h_h = (_Float16*)d_out;
  float*    out = (float*)d_out;

  char* ws = (char*)d_ws;
  size_t off = 0;
  auto alloc = [&](size_t bytes) -> void* {
    void* p = ws + off;
    off = (off + bytes + 255) & ~(size_t)255;
    return p;
  };
  _Float16* xs_h     = (_Float16*)alloc((size_t)NN * 128 * sizeof(_Float16));
  float* a_s         = (float*)alloc((size_t)NN * sizeof(float));
  float* a_d         = (float*)alloc((size_t)NN * sizeof(float));
  int*   deg         = (int*)alloc((size_t)NN * sizeof(int));
  int*   cursor      = (int*)alloc((size_t)NN * sizeof(int));
  int*   row_ptr     = (int*)alloc((size_t)(NN + 1) * sizeof(int));
  int*   src_sorted  = (int*)alloc((size_t)(E + NN) * sizeof(int));
  int*   bsum        = (int*)alloc(256 * sizeof(int));
  int*   boff        = (int*)alloc(256 * sizeof(int));
  float* u1          = (float*)alloc(256 * sizeof(float));
  float* v1          = (float*)alloc(256 * sizeof(float));
  float* u2          = (float*)alloc(256 * sizeof(float));
  float* v2          = (float*)alloc(256 * sizeof(float));

  const int NB = (NN + 255) / 256;

  cvt_kernel<<<(NN * DIN / 8 + 255) / 256, 256, 0, stream>>>(x, x_h, NN * DIN / 8);

  init_deg_kernel<<<(NN + 255) / 256, 256, 0, stream>>>(deg, NN);
  count_kernel<<<(E + 255) / 256, 256, 0, stream>>>(dst, deg, E);
  block_sums_kernel<<<NB, 256, 0, stream>>>(deg, bsum, NN);
  scan_bsums_kernel<<<1, 256, 0, stream>>>(bsum, boff, row_ptr, NB, NN);
  emit_kernel<<<NB, 256, 0, stream>>>(deg, boff, row_ptr, cursor, NN);
  scatter_kernel<<<(E + NN + 255) / 256, 256, 0, stream>>>(src, dst, cursor, src_sorted, E, NN);

  uv_kernel<<<4, 256, 0, stream>>>(w1_src, att1_src, w1_dst, att1_dst,
                                   w2_src, att2_src, w2_dst, att2_dst,
                                   u1, v1, u2, v2, DIN);

  const int wave_blocks = (NN * 64 + 255) / 256;
  const int gemm_blocks = (NN + 127) / 128;

  // ---- layer 1 ----
  gemm_mfma<256><<<gemm_blocks, 256, 0, stream>>>(x_h, w1_src, xs_h, NN);
  logits_kernel<<<wave_blocks, 256, 0, stream>>>(x_h, u1, v1, a_s, a_d, NN, DIN);
  agg_kernel<1><<<wave_blocks, 256, 0, stream>>>(row_ptr, src_sorted, a_s, a_d, xs_h, b1, h_h, NN);

  // ---- layer 2 ----
  gemm_mfma<128><<<gemm_blocks, 256, 0, stream>>>(h_h, w2_src, xs_h, NN);
  logits_kernel<<<wave_blocks, 256, 0, stream>>>(h_h, u2, v2, a_s, a_d, NN, 128);
  agg_kernel<2><<<wave_blocks, 256, 0, stream>>>(row_ptr, src_sorted, a_s, a_d, xs_h, b2, out, NN);
}

// Round 4
// 225.733 us; speedup vs baseline: 2.5078x; 1.0639x over previous
//
#include <hip/hip_runtime.h>

#define NN 50000
#define NEG_SLOPE 0.2f

typedef _Float16 half8 __attribute__((ext_vector_type(8)));
typedef _Float16 half2v __attribute__((ext_vector_type(2)));
typedef float floatx4 __attribute__((ext_vector_type(4)));

// ---------------- f32 -> f16 convert (8 elem/thread) ----------------
__global__ void cvt_kernel(const float* __restrict__ in, _Float16* __restrict__ out, int n8) {
  int i = blockIdx.x * blockDim.x + threadIdx.x;
  if (i >= n8) return;
  const float4* p = reinterpret_cast<const float4*>(in) + i * 2;
  float4 v0 = p[0], v1 = p[1];
  half8 h = {(_Float16)v0.x, (_Float16)v0.y, (_Float16)v0.z, (_Float16)v0.w,
             (_Float16)v1.x, (_Float16)v1.y, (_Float16)v1.z, (_Float16)v1.w};
  *reinterpret_cast<half8*>(out + (size_t)i * 8) = h;
}

// ---------------- graph build ----------------
__global__ void init_deg_kernel(int* deg, int n) {
  int i = blockIdx.x * blockDim.x + threadIdx.x;
  if (i < n) deg[i] = 1;  // self loop
}

// ILP-8: 8 independent fire-and-forget atomics per thread
__global__ __launch_bounds__(256) void count_kernel(const int* __restrict__ dst, int* deg, int e) {
  int i0 = (blockIdx.x * blockDim.x + threadIdx.x) * 8;
#pragma unroll
  for (int j = 0; j < 8; ++j) {
    int i = i0 + j;
    if (i < e) atomicAdd(&deg[dst[i]], 1);
  }
}

__global__ __launch_bounds__(256) void block_sums_kernel(const int* __restrict__ deg,
                                                         int* bsum, int n) {
  __shared__ int sh[256];
  int t = threadIdx.x;
  int i = blockIdx.x * 256 + t;
  sh[t] = (i < n) ? deg[i] : 0;
  __syncthreads();
  for (int off = 128; off; off >>= 1) {
    if (t < off) sh[t] += sh[t + off];
    __syncthreads();
  }
  if (t == 0) bsum[blockIdx.x] = sh[0];
}

__global__ __launch_bounds__(256) void scan_bsums_kernel(const int* __restrict__ bsum,
                                                         int* boff, int* row_ptr,
                                                         int nb, int n) {
  __shared__ int sh[256];
  int t = threadIdx.x;
  int orig = (t < nb) ? bsum[t] : 0;
  sh[t] = orig;
  __syncthreads();
  for (int off = 1; off < 256; off <<= 1) {
    int v = (t >= off) ? sh[t - off] : 0;
    __syncthreads();
    sh[t] += v;
    __syncthreads();
  }
  if (t < nb) boff[t] = sh[t] - orig;
  if (t == nb - 1) row_ptr[n] = sh[t];
}

__global__ __launch_bounds__(256) void emit_kernel(const int* __restrict__ deg,
                                                   const int* __restrict__ boff,
                                                   int* row_ptr, int* cursor, int n) {
  __shared__ int sh[256];
  int t = threadIdx.x;
  int i = blockIdx.x * 256 + t;
  int d = (i < n) ? deg[i] : 0;
  sh[t] = d;
  __syncthreads();
  for (int off = 1; off < 256; off <<= 1) {
    int v = (t >= off) ? sh[t - off] : 0;
    __syncthreads();
    sh[t] += v;
    __syncthreads();
  }
  int excl = sh[t] - d + boff[blockIdx.x];
  if (i < n) { row_ptr[i] = excl; cursor[i] = excl; }
}

// ILP-8 scatter: phase 1 issues 8 independent atomics; phase 2 does the stores.
__global__ __launch_bounds__(256) void scatter_kernel(const int* __restrict__ src,
                                                      const int* __restrict__ dst,
                                                      int* cursor, int* src_sorted,
                                                      int e, int n) {
  int i0 = (blockIdx.x * blockDim.x + threadIdx.x) * 8;
  int total = e + n;
  int sv[8], pos[8];
#pragma unroll
  for (int j = 0; j < 8; ++j) {
    int i = i0 + j;
    if (i < total) {
      int d, s;
      if (i < e) { d = dst[i]; s = src[i]; }
      else       { d = i - e;  s = d; }
      sv[j] = s;
      pos[j] = atomicAdd(&cursor[d], 1);
    } else {
      pos[j] = -1;
    }
  }
#pragma unroll
  for (int j = 0; j < 8; ++j)
    if (pos[j] >= 0) src_sorted[pos[j]] = sv[j];
}

// ---------------- projection vectors u = W_src@att_src, v = W_dst@att_dst ----------------
__global__ __launch_bounds__(256) void uv_kernel(const float* __restrict__ w1s, const float* __restrict__ a1s,
                                                 const float* __restrict__ w1d, const float* __restrict__ a1d,
                                                 const float* __restrict__ w2s, const float* __restrict__ a2s,
                                                 const float* __restrict__ w2d, const float* __restrict__ a2d,
                                                 float* u1, float* v1, float* u2, float* v2, int din) {
  int b = blockIdx.x, i = threadIdx.x;
  const float *w, *a;
  float* o;
  int d;
  if (b == 0) { w = w1s; a = a1s; o = u1; d = din; }
  else if (b == 1) { w = w1d; a = a1d; o = v1; d = din; }
  else if (b == 2) { w = w2s; a = a2s; o = u2; d = 128; }
  else { w = w2d; a = a2d; o = v2; d = 128; }
  if (i < d) {
    float s = 0.f;
    for (int j = 0; j < 128; ++j) s += w[i * 128 + j] * a[j];
    o[i] = s;
  }
}

// ---------------- GEMM: C[M,128](f16) = A[M,K](f16) @ B[K,128](f32) ----------------
template <int K>
__global__ __launch_bounds__(256) void gemm_mfma(const _Float16* __restrict__ A,
                                                 const float* __restrict__ B,
                                                 _Float16* __restrict__ C, int M) {
  constexpr int KP = K + 8;
  __shared__ _Float16 Bt[128 * KP];  // B^T [col][k]
  int tid = threadIdx.x;
  for (int idx = tid; idx < K * 128; idx += 256) {
    int k = idx >> 7, c = idx & 127;
    Bt[c * KP + k] = (_Float16)B[idx];
  }
  __syncthreads();

  int lane = tid & 63, wave = tid >> 6;
  int row_base = blockIdx.x * 128 + wave * 32;
  int lr = lane & 15, lk = lane >> 4;

  floatx4 acc[2][8];
#pragma unroll
  for (int fm = 0; fm < 2; ++fm)
#pragma unroll
    for (int n = 0; n < 8; ++n) acc[fm][n] = {0.f, 0.f, 0.f, 0.f};

  for (int k0 = 0; k0 < K; k0 += 32) {
    half8 a[2];
#pragma unroll
    for (int fm = 0; fm < 2; ++fm) {
      int row = row_base + fm * 16 + lr;
      half8 af = {0, 0, 0, 0, 0, 0, 0, 0};
      if (row < M) af = *reinterpret_cast<const half8*>(&A[(size_t)row * K + k0 + lk * 8]);
      a[fm] = af;
    }
    half8 b[8];
#pragma unroll
    for (int n = 0; n < 8; ++n)
      b[n] = *reinterpret_cast<const half8*>(&Bt[(n * 16 + lr) * KP + k0 + lk * 8]);
#pragma unroll
    for (int fm = 0; fm < 2; ++fm)
#pragma unroll
      for (int n = 0; n < 8; ++n)
        acc[fm][n] = __builtin_amdgcn_mfma_f32_16x16x32_f16(a[fm], b[n], acc[fm][n], 0, 0, 0);
  }

#pragma unroll
  for (int fm = 0; fm < 2; ++fm)
#pragma unroll
    for (int n = 0; n < 8; ++n)
#pragma unroll
      for (int r = 0; r < 4; ++r) {
        int row = row_base + fm * 16 + lk * 4 + r;
        if (row < M) C[(size_t)row * 128 + n * 16 + lr] = (_Float16)acc[fm][n][r];
      }
}

// ---------------- per-node logits: a_s[n] = x[n]·u, a_d[n] = x[n]·v ----------------
__global__ __launch_bounds__(256) void logits_kernel(const _Float16* __restrict__ xin,
                                                     const float* __restrict__ u,
                                                     const float* __restrict__ v,
                                                     float* a_s, float* a_d,
                                                     int n, int din) {
  int wid = (blockIdx.x * blockDim.x + threadIdx.x) >> 6;
  int lane = threadIdx.x & 63;
  if (wid >= n) return;
  float s1 = 0.f, s2 = 0.f;
  const half2v* xr = reinterpret_cast<const half2v*>(&xin[(size_t)wid * din]);
  for (int i = lane; i < din / 2; i += 64) {
    half2v xv = xr[i];
    float x0 = (float)xv[0], x1 = (float)xv[1];
    s1 += x0 * u[2 * i] + x1 * u[2 * i + 1];
    s2 += x0 * v[2 * i] + x1 * v[2 * i + 1];
  }
#pragma unroll
  for (int off = 32; off; off >>= 1) {
    s1 += __shfl_xor(s1, off);
    s2 += __shfl_xor(s2, off);
  }
  if (lane == 0) { a_s[wid] = s1; a_d[wid] = s2; }
}

// ---------------- wave-per-node softmax-aggregate (no max pass) ----------------
// 4 groups of 16 lanes, every 4th edge; lane covers 8 channels (half8).
// Software-pipelined: index 2-deep, row/logit data 1-deep prefetch.
template <int LAYER>
__global__ __launch_bounds__(256) void agg_kernel(const int* __restrict__ row_ptr,
                                                  const int* __restrict__ src_sorted,
                                                  const float* __restrict__ a_s,
                                                  const float* __restrict__ a_d,
                                                  const _Float16* __restrict__ xs,
                                                  const float* __restrict__ bias,
                                                  void* __restrict__ outp, int n) {
  int wid = (blockIdx.x * blockDim.x + threadIdx.x) >> 6;
  int lane = threadIdx.x & 63;
  if (wid >= n) return;
  int g = lane >> 4, lr = lane & 15;
  int r0 = row_ptr[wid], r1 = row_ptr[wid + 1];
  float ad = a_d[wid];

  float denom = 0.f;
  float acc[8];
#pragma unroll
  for (int j = 0; j < 8; ++j) acc[j] = 0.f;

  int i = r0 + g;
  int s_cur = (i < r1) ? src_sorted[i] : -1;
  int i2 = i + 4;
  int s_next = (i2 < r1) ? src_sorted[i2] : -1;
  half8 v_cur;
  float as_cur = 0.f;
  if (s_cur >= 0) {
    v_cur = *reinterpret_cast<const half8*>(&xs[(size_t)s_cur * 128 + lr * 8]);
    as_cur = a_s[s_cur];
  }
  while (s_cur >= 0) {
    // prefetch next edge's data
    half8 v_nx;
    float as_nx = 0.f;
    if (s_next >= 0) {
      v_nx = *reinterpret_cast<const half8*>(&xs[(size_t)s_next * 128 + lr * 8]);
      as_nx = a_s[s_next];
    }
    int i3 = i2 + 4;
    int s_nx2 = (i3 < r1) ? src_sorted[i3] : -1;

    float e = as_cur + ad;
    e = e > 0.f ? e : NEG_SLOPE * e;
    float w = __expf(e);
    denom += w;
#pragma unroll
    for (int j = 0; j < 8; ++j) acc[j] += w * (float)v_cur[j];

    s_cur = s_next; v_cur = v_nx; as_cur = as_nx;
    s_next = s_nx2; i2 = i3;
  }
  denom += __shfl_xor(denom, 16);
  denom += __shfl_xor(denom, 32);
#pragma unroll
  for (int j = 0; j < 8; ++j) {
    acc[j] += __shfl_xor(acc[j], 16);
    acc[j] += __shfl_xor(acc[j], 32);
  }
  if (g == 0) {
    float inv = 1.0f / denom;
    float o[8];
#pragma unroll
    for (int j = 0; j < 8; ++j) o[j] = acc[j] * inv + bias[lr * 8 + j];
    if (LAYER == 1) {
      half8 h;
#pragma unroll
      for (int j = 0; j < 8; ++j) h[j] = (_Float16)fmaxf(o[j], 0.f);
      *reinterpret_cast<half8*>(&((_Float16*)outp)[(size_t)wid * 128 + lr * 8]) = h;
    } else {
      float4 f0 = make_float4(o[0], o[1], o[2], o[3]);
      float4 f1 = make_float4(o[4], o[5], o[6], o[7]);
      float* op = &((float*)outp)[(size_t)wid * 128 + lr * 8];
      *reinterpret_cast<float4*>(op) = f0;
      *reinterpret_cast<float4*>(op + 4) = f1;
    }
  }
}

// ---------------- launch ----------------
extern "C" void kernel_launch(void* const* d_in, const int* in_sizes, int n_in,
                              void* d_out, int out_size, void* d_ws, size_t ws_size,
                              hipStream_t stream) {
  const float* x        = (const float*)d_in[0];
  const int*   eidx     = (const int*)d_in[1];
  const float* w1_src   = (const float*)d_in[2];
  const float* w1_dst   = (const float*)d_in[3];
  const float* att1_src = (const float*)d_in[4];
  const float* att1_dst = (const float*)d_in[5];
  const float* b1       = (const float*)d_in[6];
  const float* w2_src   = (const float*)d_in[7];
  const float* w2_dst   = (const float*)d_in[8];
  const float* att2_src = (const float*)d_in[9];
  const float* att2_dst = (const float*)d_in[10];
  const float* b2       = (const float*)d_in[11];

  const int E = in_sizes[1] / 2;
  const int DIN = in_sizes[0] / NN;  // 256
  const int* src = eidx;
  const int* dst = eidx + E;

  _Float16* x_h = (_Float16*)d_out;
  _Float16* h_h = (_Float16*)d_out;
  float*    out = (float*)d_out;

  char* ws = (char*)d_ws;
  size_t off = 0;
  auto alloc = [&](size_t bytes) -> void* {
    void* p = ws + off;
    off = (off + bytes + 255) & ~(size_t)255;
    return p;
  };
  _Float16* xs_h     = (_Float16*)alloc((size_t)NN * 128 * sizeof(_Float16));
  float* a_s         = (float*)alloc((size_t)NN * sizeof(float));
  float* a_d         = (float*)alloc((size_t)NN * sizeof(float));
  int*   deg         = (int*)alloc((size_t)NN * sizeof(int));
  int*   cursor      = (int*)alloc((size_t)NN * sizeof(int));
  int*   row_ptr     = (int*)alloc((size_t)(NN + 1) * sizeof(int));
  int*   src_sorted  = (int*)alloc((size_t)(E + NN) * sizeof(int));
  int*   bsum        = (int*)alloc(256 * sizeof(int));
  int*   boff        = (int*)alloc(256 * sizeof(int));
  float* u1          = (float*)alloc(256 * sizeof(float));
  float* v1          = (float*)alloc(256 * sizeof(float));
  float* u2          = (float*)alloc(256 * sizeof(float));
  float* v2          = (float*)alloc(256 * sizeof(float));

  const int NB = (NN + 255) / 256;

  cvt_kernel<<<(NN * DIN / 8 + 255) / 256, 256, 0, stream>>>(x, x_h, NN * DIN / 8);

  init_deg_kernel<<<(NN + 255) / 256, 256, 0, stream>>>(deg, NN);
  count_kernel<<<(E / 8 + 255) / 256, 256, 0, stream>>>(dst, deg, E);
  block_sums_kernel<<<NB, 256, 0, stream>>>(deg, bsum, NN);
  scan_bsums_kernel<<<1, 256, 0, stream>>>(bsum, boff, row_ptr, NB, NN);
  emit_kernel<<<NB, 256, 0, stream>>>(deg, boff, row_ptr, cursor, NN);
  scatter_kernel<<<((E + NN) / 8 + 255) / 256, 256, 0, stream>>>(src, dst, cursor, src_sorted, E, NN);

  uv_kernel<<<4, 256, 0, stream>>>(w1_src, att1_src, w1_dst, att1_dst,
                                   w2_src, att2_src, w2_dst, att2_dst,
                                   u1, v1, u2, v2, DIN);

  const int wave_blocks = (NN * 64 + 255) / 256;
  const int gemm_blocks = (NN + 127) / 128;

  // ---- layer 1 ----
  gemm_mfma<256><<<gemm_blocks, 256, 0, stream>>>(x_h, w1_src, xs_h, NN);
  logits_kernel<<<wave_blocks, 256, 0, stream>>>(x_h, u1, v1, a_s, a_d, NN, DIN);
  agg_kernel<1><<<wave_blocks, 256, 0, stream>>>(row_ptr, src_sorted, a_s, a_d, xs_h, b1, h_h, NN);

  // ---- layer 2 ----
  gemm_mfma<128><<<gemm_blocks, 256, 0, stream>>>(h_h, w2_src, xs_h, NN);
  logits_kernel<<<wave_blocks, 256, 0, stream>>>(h_h, u2, v2, a_s, a_d, NN, 128);
  agg_kernel<2><<<wave_blocks, 256, 0, stream>>>(row_ptr, src_sorted, a_s, a_d, xs_h, b2, out, NN);
}

// Round 5
// 211.021 us; speedup vs baseline: 2.6826x; 1.0697x over previous
//
#include <hip/hip_runtime.h>

#define NN 50000
#define NEG_SLOPE 0.2f

typedef _Float16 half8 __attribute__((ext_vector_type(8)));
typedef _Float16 half2v __attribute__((ext_vector_type(2)));
typedef float floatx4 __attribute__((ext_vector_type(4)));

// ================= scan chain (small) =================

__global__ __launch_bounds__(256) void block_sums_kernel(const int* __restrict__ deg,
                                                         int* bsum, int n) {
  __shared__ int sh[256];
  int t = threadIdx.x;
  int i = blockIdx.x * 256 + t;
  sh[t] = (i < n) ? deg[i] + 1 : 0;  // +1 self loop
  __syncthreads();
  for (int off = 128; off; off >>= 1) {
    if (t < off) sh[t] += sh[t + off];
    __syncthreads();
  }
  if (t == 0) bsum[blockIdx.x] = sh[0];
}

__global__ __launch_bounds__(256) void scan_bsums_kernel(const int* __restrict__ bsum,
                                                         int* boff, int* row_ptr,
                                                         int nb, int n) {
  __shared__ int sh[256];
  int t = threadIdx.x;
  int orig = (t < nb) ? bsum[t] : 0;
  sh[t] = orig;
  __syncthreads();
  for (int off = 1; off < 256; off <<= 1) {
    int v = (t >= off) ? sh[t - off] : 0;
    __syncthreads();
    sh[t] += v;
    __syncthreads();
  }
  if (t < nb) boff[t] = sh[t] - orig;
  if (t == nb - 1) row_ptr[n] = sh[t];
}

__global__ __launch_bounds__(256) void emit_kernel(const int* __restrict__ deg,
                                                   const int* __restrict__ boff,
                                                   int* row_ptr, int* cursor, int n) {
  __shared__ int sh[256];
  int t = threadIdx.x;
  int i = blockIdx.x * 256 + t;
  int d = (i < n) ? deg[i] + 1 : 0;  // +1 self loop
  sh[t] = d;
  __syncthreads();
  for (int off = 1; off < 256; off <<= 1) {
    int v = (t >= off) ? sh[t - off] : 0;
    __syncthreads();
    sh[t] += v;
    __syncthreads();
  }
  int excl = sh[t] - d + boff[blockIdx.x];
  if (i < n) { row_ptr[i] = excl; cursor[i] = excl; }
}

// ================= prep: count atomics || uv GEMVs || f32->f16 cvt =================

__global__ __launch_bounds__(256) void prep_kernel(
    const int* __restrict__ dst, int* deg, int e, int G_CNT,
    const float* __restrict__ w1s, const float* __restrict__ a1s,
    const float* __restrict__ w1d, const float* __restrict__ a1d,
    const float* __restrict__ w2s, const float* __restrict__ a2s,
    const float* __restrict__ w2d, const float* __restrict__ a2d,
    float* u1, float* v1, float* u2, float* v2, int din,
    const float* __restrict__ x, _Float16* __restrict__ xh, int n8) {
  int bid = blockIdx.x, tid = threadIdx.x;
  if (bid < G_CNT) {
    int i0 = (bid * 256 + tid) * 8;
#pragma unroll
    for (int j = 0; j < 8; ++j) {
      int i = i0 + j;
      if (i < e) atomicAdd(&deg[dst[i]], 1);
    }
  } else if (bid < G_CNT + 4) {
    int b = bid - G_CNT;
    const float *w, *a;
    float* o;
    int d;
    if (b == 0) { w = w1s; a = a1s; o = u1; d = din; }
    else if (b == 1) { w = w1d; a = a1d; o = v1; d = din; }
    else if (b == 2) { w = w2s; a = a2s; o = u2; d = 128; }
    else { w = w2d; a = a2d; o = v2; d = 128; }
    if (tid < d) {
      float s = 0.f;
      for (int j = 0; j < 128; ++j) s += w[tid * 128 + j] * a[j];
      o[tid] = s;
    }
  } else {
    int i = (bid - G_CNT - 4) * 256 + tid;
    if (i >= n8) return;
    const float4* p = reinterpret_cast<const float4*>(x) + i * 2;
    float4 v0 = p[0], v1 = p[1];
    half8 h = {(_Float16)v0.x, (_Float16)v0.y, (_Float16)v0.z, (_Float16)v0.w,
               (_Float16)v1.x, (_Float16)v1.y, (_Float16)v1.z, (_Float16)v1.w};
    *reinterpret_cast<half8*>(xh + (size_t)i * 8) = h;
  }
}

// ================= fused: gemm(MFMA) || scatter-atomics || logits =================
// gemm: C[M,128](f16) = A[M,K](f16) @ B[K,128](f32), LDS-chunked KC=128 (34.8KB)

template <int K>
__global__ __launch_bounds__(256) void fused_kernel(
    const _Float16* __restrict__ A, const float* __restrict__ B,
    _Float16* __restrict__ C, int M, int G_GEMM,
    const int* __restrict__ src, const int* __restrict__ dst,
    int* cursor, int* src_sorted, int e, int G_SCAT,
    const _Float16* __restrict__ xin, const float* __restrict__ u,
    const float* __restrict__ v, float* a_s, float* a_d, int din) {
  __shared__ _Float16 Bt[128 * 136];
  int bid = blockIdx.x, tid = threadIdx.x;
  if (bid < G_GEMM) {
    constexpr int KP = 136;
    int lane = tid & 63, wave = tid >> 6;
    int row_base = bid * 128 + wave * 32;
    int lr = lane & 15, lk = lane >> 4;
    floatx4 acc[2][8];
#pragma unroll
    for (int fm = 0; fm < 2; ++fm)
#pragma unroll
      for (int q = 0; q < 8; ++q) acc[fm][q] = {0.f, 0.f, 0.f, 0.f};
    for (int kc = 0; kc < K; kc += 128) {
      for (int idx = tid; idx < 128 * 128; idx += 256) {
        int k = idx >> 7, c = idx & 127;
        Bt[c * KP + k] = (_Float16)B[(size_t)(kc + k) * 128 + c];
      }
      __syncthreads();
#pragma unroll
      for (int k0 = 0; k0 < 128; k0 += 32) {
        half8 a[2];
#pragma unroll
        for (int fm = 0; fm < 2; ++fm) {
          int row = row_base + fm * 16 + lr;
          half8 af = {0, 0, 0, 0, 0, 0, 0, 0};
          if (row < M) af = *reinterpret_cast<const half8*>(&A[(size_t)row * K + kc + k0 + lk * 8]);
          a[fm] = af;
        }
        half8 b[8];
#pragma unroll
        for (int q = 0; q < 8; ++q)
          b[q] = *reinterpret_cast<const half8*>(&Bt[(q * 16 + lr) * KP + k0 + lk * 8]);
#pragma unroll
        for (int fm = 0; fm < 2; ++fm)
#pragma unroll
          for (int q = 0; q < 8; ++q)
            acc[fm][q] = __builtin_amdgcn_mfma_f32_16x16x32_f16(a[fm], b[q], acc[fm][q], 0, 0, 0);
      }
      __syncthreads();
    }
#pragma unroll
    for (int fm = 0; fm < 2; ++fm)
#pragma unroll
      for (int q = 0; q < 8; ++q)
#pragma unroll
        for (int r = 0; r < 4; ++r) {
          int row = row_base + fm * 16 + lk * 4 + r;
          if (row < M) C[(size_t)row * 128 + q * 16 + lr] = (_Float16)acc[fm][q][r];
        }
  } else if (bid < G_GEMM + G_SCAT) {
    int sbid = bid - G_GEMM;
    int i0 = (sbid * 256 + tid) * 8;
    int total = e + NN;
    int sv[8], pos[8];
#pragma unroll
    for (int j = 0; j < 8; ++j) {
      int i = i0 + j;
      if (i < total) {
        int d, s;
        if (i < e) { d = dst[i]; s = src[i]; }
        else       { d = i - e;  s = d; }
        sv[j] = s;
        pos[j] = atomicAdd(&cursor[d], 1);
      } else pos[j] = -1;
    }
#pragma unroll
    for (int j = 0; j < 8; ++j)
      if (pos[j] >= 0) src_sorted[pos[j]] = sv[j];
  } else {
    int lbid = bid - G_GEMM - G_SCAT;
    int wid = lbid * 4 + (tid >> 6);
    int lane = tid & 63;
    if (wid >= NN) return;
    float s1 = 0.f, s2 = 0.f;
    const half2v* xr = reinterpret_cast<const half2v*>(&xin[(size_t)wid * din]);
    for (int i = lane; i < din / 2; i += 64) {
      half2v xv = xr[i];
      float x0 = (float)xv[0], x1 = (float)xv[1];
      s1 += x0 * u[2 * i] + x1 * u[2 * i + 1];
      s2 += x0 * v[2 * i] + x1 * v[2 * i + 1];
    }
#pragma unroll
    for (int off = 32; off; off >>= 1) {
      s1 += __shfl_xor(s1, off);
      s2 += __shfl_xor(s2, off);
    }
    if (lane == 0) { a_s[wid] = s1; a_d[wid] = s2; }
  }
}

// ================= wave-per-node softmax-aggregate =================
// 8 groups of 8 lanes, every 8th edge; lane covers 16 channels (2x half8).
template <int LAYER>
__global__ __launch_bounds__(256) void agg_kernel(const int* __restrict__ row_ptr,
                                                  const int* __restrict__ src_sorted,
                                                  const float* __restrict__ a_s,
                                                  const float* __restrict__ a_d,
                                                  const _Float16* __restrict__ xs,
                                                  const float* __restrict__ bias,
                                                  void* __restrict__ outp, int n) {
  int wid = (blockIdx.x * blockDim.x + threadIdx.x) >> 6;
  int lane = threadIdx.x & 63;
  if (wid >= n) return;
  int g = lane >> 3, lr = lane & 7;
  int r0 = row_ptr[wid], r1 = row_ptr[wid + 1];
  float ad = a_d[wid];

  float denom = 0.f;
  float acc[16];
#pragma unroll
  for (int j = 0; j < 16; ++j) acc[j] = 0.f;

  int i = r0 + g;
  int s_cur = (i < r1) ? src_sorted[i] : -1;
  int i2 = i + 8;
  int s_next = (i2 < r1) ? src_sorted[i2] : -1;
  half8 v_cur0, v_cur1;
  float as_cur = 0.f;
  if (s_cur >= 0) {
    const _Float16* pr = &xs[(size_t)s_cur * 128 + lr * 16];
    v_cur0 = *reinterpret_cast<const half8*>(pr);
    v_cur1 = *reinterpret_cast<const half8*>(pr + 8);
    as_cur = a_s[s_cur];
  }
  while (s_cur >= 0) {
    half8 v_nx0, v_nx1;
    float as_nx = 0.f;
    if (s_next >= 0) {
      const _Float16* pr = &xs[(size_t)s_next * 128 + lr * 16];
      v_nx0 = *reinterpret_cast<const half8*>(pr);
      v_nx1 = *reinterpret_cast<const half8*>(pr + 8);
      as_nx = a_s[s_next];
    }
    int i3 = i2 + 8;
    int s_nx2 = (i3 < r1) ? src_sorted[i3] : -1;

    float e = as_cur + ad;
    e = e > 0.f ? e : NEG_SLOPE * e;
    float w = __expf(e);
    denom += w;
#pragma unroll
    for (int j = 0; j < 8; ++j) {
      acc[j] += w * (float)v_cur0[j];
      acc[8 + j] += w * (float)v_cur1[j];
    }
    s_cur = s_next; v_cur0 = v_nx0; v_cur1 = v_nx1; as_cur = as_nx;
    s_next = s_nx2; i2 = i3;
  }
  denom += __shfl_xor(denom, 8);
  denom += __shfl_xor(denom, 16);
  denom += __shfl_xor(denom, 32);
#pragma unroll
  for (int j = 0; j < 16; ++j) {
    acc[j] += __shfl_xor(acc[j], 8);
    acc[j] += __shfl_xor(acc[j], 16);
    acc[j] += __shfl_xor(acc[j], 32);
  }
  if (g == 0) {
    float inv = 1.0f / denom;
    float o[16];
#pragma unroll
    for (int j = 0; j < 16; ++j) o[j] = acc[j] * inv + bias[lr * 16 + j];
    if (LAYER == 1) {
      half8 h0, h1;
#pragma unroll
      for (int j = 0; j < 8; ++j) {
        h0[j] = (_Float16)fmaxf(o[j], 0.f);
        h1[j] = (_Float16)fmaxf(o[8 + j], 0.f);
      }
      _Float16* op = &((_Float16*)outp)[(size_t)wid * 128 + lr * 16];
      *reinterpret_cast<half8*>(op) = h0;
      *reinterpret_cast<half8*>(op + 8) = h1;
    } else {
      float* op = &((float*)outp)[(size_t)wid * 128 + lr * 16];
#pragma unroll
      for (int q = 0; q < 4; ++q) {
        float4 f = make_float4(o[q * 4], o[q * 4 + 1], o[q * 4 + 2], o[q * 4 + 3]);
        *reinterpret_cast<float4*>(op + q * 4) = f;
      }
    }
  }
}

// ================= launch =================
extern "C" void kernel_launch(void* const* d_in, const int* in_sizes, int n_in,
                              void* d_out, int out_size, void* d_ws, size_t ws_size,
                              hipStream_t stream) {
  const float* x        = (const float*)d_in[0];
  const int*   eidx     = (const int*)d_in[1];
  const float* w1_src   = (const float*)d_in[2];
  const float* w1_dst   = (const float*)d_in[3];
  const float* att1_src = (const float*)d_in[4];
  const float* att1_dst = (const float*)d_in[5];
  const float* b1       = (const float*)d_in[6];
  const float* w2_src   = (const float*)d_in[7];
  const float* w2_dst   = (const float*)d_in[8];
  const float* att2_src = (const float*)d_in[9];
  const float* att2_dst = (const float*)d_in[10];
  const float* b2       = (const float*)d_in[11];

  const int E = in_sizes[1] / 2;
  const int DIN = in_sizes[0] / NN;  // 256
  const int* src = eidx;
  const int* dst = eidx + E;

  _Float16* x_h = (_Float16*)d_out;   // [NN,256] f16 == 25.6MB == d_out
  _Float16* h_h = (_Float16*)d_out;   // layer-1 out overwrites dead half
  float*    out = (float*)d_out;

  char* ws = (char*)d_ws;
  size_t off = 0;
  auto alloc = [&](size_t bytes) -> void* {
    void* p = ws + off;
    off = (off + bytes + 255) & ~(size_t)255;
    return p;
  };
  _Float16* xs_h     = (_Float16*)alloc((size_t)NN * 128 * sizeof(_Float16));
  float* a_s         = (float*)alloc((size_t)NN * sizeof(float));
  float* a_d         = (float*)alloc((size_t)NN * sizeof(float));
  int*   deg         = (int*)alloc((size_t)NN * sizeof(int));
  int*   cursor      = (int*)alloc((size_t)NN * sizeof(int));
  int*   row_ptr     = (int*)alloc((size_t)(NN + 1) * sizeof(int));
  int*   src_sorted  = (int*)alloc((size_t)(E + NN) * sizeof(int));
  int*   bsum        = (int*)alloc(256 * sizeof(int));
  int*   boff        = (int*)alloc(256 * sizeof(int));
  float* u1          = (float*)alloc(256 * sizeof(float));
  float* v1          = (float*)alloc(256 * sizeof(float));
  float* u2          = (float*)alloc(256 * sizeof(float));
  float* v2          = (float*)alloc(256 * sizeof(float));

  const int NB = (NN + 255) / 256;            // 196
  const int G_CNT = (E / 8 + 255) / 256;      // 391
  const int G_CVT = (NN * DIN / 8 + 255) / 256;
  const int G_SCAT = ((E + NN) / 8 + 255) / 256;
  const int G_GEMM = (NN + 127) / 128;        // 391
  const int G_LOG = (NN + 3) / 4;             // 12500
  const int wave_blocks = (NN * 64 + 255) / 256;

  hipMemsetAsync(deg, 0, NN * sizeof(int), stream);

  prep_kernel<<<G_CNT + 4 + G_CVT, 256, 0, stream>>>(
      dst, deg, E, G_CNT,
      w1_src, att1_src, w1_dst, att1_dst, w2_src, att2_src, w2_dst, att2_dst,
      u1, v1, u2, v2, DIN, x, x_h, NN * DIN / 8);

  block_sums_kernel<<<NB, 256, 0, stream>>>(deg, bsum, NN);
  scan_bsums_kernel<<<1, 256, 0, stream>>>(bsum, boff, row_ptr, NB, NN);
  emit_kernel<<<NB, 256, 0, stream>>>(deg, boff, row_ptr, cursor, NN);

  // ---- layer 1: gemm1 || scatter || logits1 ----
  fused_kernel<256><<<G_GEMM + G_SCAT + G_LOG, 256, 0, stream>>>(
      x_h, w1_src, xs_h, NN, G_GEMM,
      src, dst, cursor, src_sorted, E, G_SCAT,
      x_h, u1, v1, a_s, a_d, DIN);
  agg_kernel<1><<<wave_blocks, 256, 0, stream>>>(row_ptr, src_sorted, a_s, a_d, xs_h, b1, h_h, NN);

  // ---- layer 2: gemm2 || logits2 ----
  fused_kernel<128><<<G_GEMM + 0 + G_LOG, 256, 0, stream>>>(
      h_h, w2_src, xs_h, NN, G_GEMM,
      src, dst, cursor, src_sorted, E, 0,
      h_h, u2, v2, a_s, a_d, 128);
  agg_kernel<2><<<wave_blocks, 256, 0, stream>>>(row_ptr, src_sorted, a_s, a_d, xs_h, b2, out, NN);
}